// Round 14
// baseline (154.997 us; speedup 1.0000x reference)
//
#include <hip/hip_runtime.h>

typedef __attribute__((ext_vector_type(8))) _Float16 f16x8;
typedef __attribute__((ext_vector_type(4))) float    f32x4;

constexpr int Bsz = 32768;
constexpr int Hn  = 256;
constexpr int In  = 128;
constexpr long long BH = (long long)Bsz * Hn;

// ---------------------------------------------------------------------------
// prep: weights -> fp16, PRE-SWIZZLED into MFMA-fragment-linear order.
// Tile (cg, t): lane l holds W[cg*16 + (l&15)][t*32 + (l>>4)*8 ..+8],
// stored at ((cg*NT + t)*64 + l)*8 halves.
// ws half-layout: Gh [0,64K) | Gm [64K,128K) | Wr [128K,192K) | Wi [192K,224K)
// ---------------------------------------------------------------------------
__global__ __launch_bounds__(256) void k_prep(
    const float* __restrict__ Wi, const float* __restrict__ Wr,
    const float* __restrict__ Gc, _Float16* __restrict__ ws)
{
    const int idx = blockIdx.x * 256 + threadIdx.x;   // 0..65535
    {   // Gh/Gm/Wr: K=256, NT=8
        const int cg = idx >> 12, rem = idx & 4095;
        const int t = rem >> 9, l = (rem >> 3) & 63, j = idx & 7;
        const int col = cg * 16 + (l & 15);
        const int k   = t * 32 + (l >> 4) * 8 + j;
        float g = Gc[col * Hn + k];
        _Float16 gh = (_Float16)g;
        ws[idx]         = gh;
        ws[65536 + idx] = (_Float16)((g - (float)gh) * 4096.0f);
        ws[131072 + idx] = (_Float16)Wr[col * Hn + k];
    }
    if (idx < 32768) {  // Wi: K=128, NT=4
        const int cg = idx >> 11, rem = idx & 2047;
        const int t = rem >> 9, l = (rem >> 3) & 63, j = idx & 7;
        const int col = cg * 16 + (l & 15);
        const int k   = t * 32 + (l >> 4) * 8 + j;
        ws[196608 + idx] = (_Float16)Wi[col * In + k];
    }
}

// fragment converts (same values/order as R11's staged path)
__device__ __forceinline__ f16x8 cvt_hi2(float4 a, float4 b) {
    float f[8] = {a.x, a.y, a.z, a.w, b.x, b.y, b.z, b.w};
    f16x8 r;
    #pragma unroll
    for (int k = 0; k < 8; ++k) r[k] = (_Float16)f[k];
    return r;
}
__device__ __forceinline__ f16x8 cvt_mid2(float4 a, float4 b) {
    float f[8] = {a.x, a.y, a.z, a.w, b.x, b.y, b.z, b.w};
    f16x8 r;
    #pragma unroll
    for (int k = 0; k < 8; ++k) {
        _Float16 h = (_Float16)f[k];
        r[k] = (_Float16)((f[k] - (float)h) * 4096.0f);
    }
    return r;
}

#define MFMA16(A, B, C) __builtin_amdgcn_mfma_f32_16x16x32_f16(A, B, C, 0, 0, 0)

// ---------------------------------------------------------------------------
// main: 1024 blocks x 512 thr (8 waves), BT=32 rows, wave owns 2 col-groups.
// ZERO LDS, ZERO barriers: A-fragments straight from global (sector-clean:
// 16 rows x full 64B lines per wave-load; all 8 waves share the same A chunk
// -> L1 serves the repeats). B-fragments from pre-swizzled fp16 weights
// (coalesced, L2-resident). Epilogue scatters directly from the fragment
// layout (64-B sector-aligned). Waves free-run -> no phase lockstep.
// Fragment values + MFMA order identical to R11 (bit-identical outputs).
// ---------------------------------------------------------------------------
__global__ __launch_bounds__(512, 4) void k_main(
    const float* __restrict__ x, const float* __restrict__ z,
    const float* __restrict__ v, const float* __restrict__ cur,
    const float* __restrict__ rho, const _Float16* __restrict__ ws,
    float* __restrict__ out)
{
    const int tid  = threadIdx.x;         // 0..511
    const int lane = tid & 63;
    const int ln = lane & 15, lg = lane >> 4;
    const int w  = tid >> 6;              // wave 0..7
    const int rowBase = blockIdx.x * 32;

    const _Float16* Gh  = ws;
    const _Float16* Gm  = ws + 65536;
    const _Float16* Wr  = ws + 131072;
    const _Float16* Wi  = ws + 196608;

    f32x4 acc_c[2][2], acc_cm[2][2], acc_i[2][2];
    #pragma unroll
    for (int m = 0; m < 2; ++m)
        #pragma unroll
        for (int c = 0; c < 2; ++c) {
            acc_c[m][c]  = (f32x4){0.f, 0.f, 0.f, 0.f};
            acc_cm[m][c] = (f32x4){0.f, 0.f, 0.f, 0.f};
            acc_i[m][c]  = (f32x4){0.f, 0.f, 0.f, 0.f};
        }

    // per-lane A row pointers (rows ln and ln+16 of this block's stripe)
    const float* vr0 = v + (size_t)(rowBase + ln) * Hn;
    const float* vr1 = vr0 + 16 * Hn;
    const float* zr0 = z + (size_t)(rowBase + ln) * Hn;
    const float* zr1 = zr0 + 16 * Hn;
    const float* xr0 = x + (size_t)(rowBase + ln) * In;
    const float* xr1 = xr0 + 16 * In;

    #pragma unroll 2
    for (int t = 0; t < 8; ++t) {
        const int kf = t * 32 + lg * 8;   // this lane's k-chunk (floats)
        // ---- A fragments from global: 16 rows x 128B per pair of loads ----
        float4 va00 = *(const float4*)(vr0 + kf);
        float4 va01 = *(const float4*)(vr0 + kf + 4);
        float4 va10 = *(const float4*)(vr1 + kf);
        float4 va11 = *(const float4*)(vr1 + kf + 4);
        float4 za00 = *(const float4*)(zr0 + kf);
        float4 za01 = *(const float4*)(zr0 + kf + 4);
        float4 za10 = *(const float4*)(zr1 + kf);
        float4 za11 = *(const float4*)(zr1 + kf + 4);
        f16x8 vh0 = cvt_hi2(va00, va01),  vh1 = cvt_hi2(va10, va11);
        f16x8 vm0 = cvt_mid2(va00, va01), vm1 = cvt_mid2(va10, va11);
        f16x8 zh0 = cvt_hi2(za00, za01),  zh1 = cvt_hi2(za10, za11);
        f16x8 xh0, xh1;
        if (t < 4) {
            float4 xa00 = *(const float4*)(xr0 + kf);
            float4 xa01 = *(const float4*)(xr0 + kf + 4);
            float4 xa10 = *(const float4*)(xr1 + kf);
            float4 xa11 = *(const float4*)(xr1 + kf + 4);
            xh0 = cvt_hi2(xa00, xa01);
            xh1 = cvt_hi2(xa10, xa11);
        }
        // ---- B fragments: pre-swizzled, coalesced, L2-resident ----
        #pragma unroll
        for (int c = 0; c < 2; ++c) {
            const int cg = w * 2 + c;
            f16x8 bgh = *(const f16x8*)(Gh + ((size_t)(cg * 8 + t) * 64 + lane) * 8);
            f16x8 bgm = *(const f16x8*)(Gm + ((size_t)(cg * 8 + t) * 64 + lane) * 8);
            f16x8 bwr = *(const f16x8*)(Wr + ((size_t)(cg * 8 + t) * 64 + lane) * 8);
            acc_c[0][c]  = MFMA16(vh0, bgh, acc_c[0][c]);
            acc_c[1][c]  = MFMA16(vh1, bgh, acc_c[1][c]);
            acc_cm[0][c] = MFMA16(vh0, bgm, acc_cm[0][c]);
            acc_cm[1][c] = MFMA16(vh1, bgm, acc_cm[1][c]);
            acc_cm[0][c] = MFMA16(vm0, bgh, acc_cm[0][c]);
            acc_cm[1][c] = MFMA16(vm1, bgh, acc_cm[1][c]);
            acc_i[0][c]  = MFMA16(zh0, bwr, acc_i[0][c]);
            acc_i[1][c]  = MFMA16(zh1, bwr, acc_i[1][c]);
            if (t < 4) {
                f16x8 bwi = *(const f16x8*)(Wi + ((size_t)(cg * 4 + t) * 64 + lane) * 8);
                acc_i[0][c] = MFMA16(xh0, bwi, acc_i[0][c]);
                acc_i[1][c] = MFMA16(xh1, bwi, acc_i[1][c]);
            }
        }
    }

    // fold split-fp16 correction: coupling = acc_c + acc_cm / 4096
    #pragma unroll
    for (int m = 0; m < 2; ++m)
        #pragma unroll
        for (int c = 0; c < 2; ++c)
            acc_c[m][c] = acc_c[m][c] + acc_cm[m][c] * 2.44140625e-4f;

    float* out_z   = out;
    float* out_v   = out + BH;
    float* out_i   = out + 2 * BH;
    float* out_rho = out + 3 * BH;

    // ---- epilogue: direct scatter from fragment layout (sector-aligned) ----
    #pragma unroll
    for (int m = 0; m < 2; ++m)
        #pragma unroll
        for (int c = 0; c < 2; ++c) {
            const int col = (w * 2 + c) * 16 + ln;
            const int rowb = rowBase + m * 16 + lg * 4;
            #pragma unroll
            for (int r = 0; r < 4; ++r) {
                const size_t idx = (size_t)(rowb + r) * Hn + col;
                const float vv = v[idx];
                const float ii = cur[idx];
                const float rh = rho[idx];
                float dv   = 0.1f * ((0.0f - vv) + ii) + acc_c[m][c][r];
                float vdec = vv + dv;
                float zf   = (vdec - 1.0f) > 0.0f ? 1.0f : 0.0f;
                float vnew = (1.0f - zf) * vdec;              // V_RESET = 0
                float mask = rh > 0.0f ? 1.0f : 0.0f;
                vnew = (1.0f - mask) * vnew + mask * vv;
                zf   = (1.0f - mask) * zf;
                float rhon = (1.0f - zf) * fmaxf(rh - mask, 0.0f) + zf * 5.0f;
                out_z[idx]   = zf;
                out_v[idx]   = vnew;
                out_rho[idx] = rhon;
                out_i[idx]   = 0.8f * ii + acc_i[m][c][r];
            }
        }
}

extern "C" void kernel_launch(void* const* d_in, const int* in_sizes, int n_in,
                              void* d_out, int out_size, void* d_ws, size_t ws_size,
                              hipStream_t stream) {
    const float* x   = (const float*)d_in[0];
    const float* z   = (const float*)d_in[1];
    const float* v   = (const float*)d_in[2];
    const float* cur = (const float*)d_in[3];
    const float* rho = (const float*)d_in[4];
    const float* Wi  = (const float*)d_in[5];
    const float* Wr  = (const float*)d_in[6];
    const float* Gc  = (const float*)d_in[7];
    float* out = (float*)d_out;
    _Float16* ws = (_Float16*)d_ws;   // needs 458752 B

    hipLaunchKernelGGL(k_prep, dim3(256), dim3(256), 0, stream, Wi, Wr, Gc, ws);
    hipLaunchKernelGGL(k_main, dim3(Bsz / 32), dim3(512), 0, stream,
                       x, z, v, cur, rho, ws, out);
}